// Round 2
// baseline (13991.347 us; speedup 1.0000x reference)
//
#include <hip/hip_runtime.h>
#include <stdint.h>

// LSTM_Trend: B=256, T=512, F=64, H=512, P=24.
// Persistent kernel: 256 WGs = 8 batch-groups (32 batches) x 32 hidden-groups
// (16 h-units -> 64 gate columns). Weights live in registers as MFMA
// B-fragments (K = 512 (W_hh) + 64 (W_ih) = 576); the input projection is
// folded into the recurrence GEMM. Per-step 32-WG group barrier over
// device-scope atomics; h double-buffered (bf16) in d_ws.
// Input dtype (fp32 vs bf16) is sniffed at runtime from b_ih: reading an
// fp32 array as bf16 makes half the values have uniform-random exponents,
// so "any |b_ih[i]| > 1" <=> fp32 (P(miss) ~ 0.5^128).

namespace {
constexpr int T_STEPS = 512;
constexpr int FEA  = 64;
constexpr int HID  = 512;
constexpr int KTOT = HID + FEA;   // 576
constexpr int KPAD = KTOT + 8;    // 584 (pad keeps ds_read_b128 conflict-free)
constexpr int NKI  = KTOT / 32;   // 18 K-iterations
constexpr int GSTR = 68;          // gates LDS row stride (floats)
constexpr size_t HBUF_ELEMS = 2ull * 256 * 512;     // double-buffered h (bf16)
constexpr size_t BAR_OFF    = HBUF_ELEMS * 2;       // byte offset of counters

typedef __bf16   bf16x8 __attribute__((ext_vector_type(8)));
typedef uint16_t u16x8  __attribute__((ext_vector_type(8)));
typedef float    f32x4  __attribute__((ext_vector_type(4)));

union V8 { u16x8 u; bf16x8 b; uint4 q; };

__device__ __forceinline__ float bf2f(uint16_t u) {
  union { uint32_t i; float f; } v; v.i = (uint32_t)u << 16; return v.f;
}
__device__ __forceinline__ uint16_t f2bf(float f) {
  union { float f; uint32_t i; } v; v.f = f;
  uint32_t x = v.i;
  return (uint16_t)((x + 0x7FFFu + ((x >> 16) & 1u)) >> 16);  // RNE
}
__device__ __forceinline__ float sigmoid_f(float x) {
  return 1.0f / (1.0f + __expf(-x));
}
__device__ __forceinline__ float tanh_f(float x) {
  float e = __expf(-2.0f * fabsf(x));          // e in (0,1]: overflow-safe
  float t = (1.0f - e) / (1.0f + e);
  return copysignf(t, x);
}
// 8 consecutive elements starting at elem_off, as bf16 fragment.
__device__ __forceinline__ bf16x8 load8(const void* base, size_t elem_off,
                                        bool fp32m) {
  V8 r;
  if (fp32m) {
    const float* p = (const float*)base + elem_off;
#pragma unroll
    for (int i = 0; i < 8; ++i) r.u[i] = f2bf(p[i]);
  } else {
    r.q = *(const uint4*)((const uint16_t*)base + elem_off);
  }
  return r.b;
}
__device__ __forceinline__ float loadf(const void* base, int idx, bool fp32m) {
  return fp32m ? ((const float*)base)[idx] : bf2f(((const uint16_t*)base)[idx]);
}
} // namespace

__global__ __launch_bounds__(256, 1) void lstm_persistent(
    const void* __restrict__ x,      // [256][512][64]
    const void* __restrict__ W_ih,   // [2048][64]
    const void* __restrict__ W_hh,   // [2048][512]
    const void* __restrict__ b_ih,   // [2048]
    const void* __restrict__ b_hh,   // [2048]
    const void* __restrict__ W_fc,   // [1536][512]
    const void* __restrict__ b_fc,   // [1536]
    void* __restrict__ out,          // [256][1536]
    uint16_t* __restrict__ hbuf,     // [2][256][512] bf16 (workspace)
    uint32_t* __restrict__ bar)      // 8 counters, stride 64 uints
{
  __shared__ uint16_t Als[32 * KPAD];    // A tile: [h_{t-1} | x_t], 32 rows
  __shared__ float    Gls[32 * GSTR];    // gate pre-activations, fp32
  __shared__ int      sflag;

  const int tid = threadIdx.x;
  const int wv  = tid >> 6;              // wave 0..3
  const int ln  = tid & 63;
  const int nl  = ln & 15;               // MFMA m/n lane index
  const int kq  = ln >> 4;               // MFMA k-quad
  const int bg  = blockIdx.x & 7;        // batch group (XCD-affine)
  const int hg  = blockIdx.x >> 3;       // hidden group 0..31

  // ---- dtype sniff (block-uniform) ----
  if (tid == 0) sflag = 0;
  __syncthreads();
  {
    float a = fabsf(bf2f(((const uint16_t*)b_ih)[tid]));
    if (a > 1.0f) atomicOr(&sflag, 1);
  }
  __syncthreads();
  const bool fp32m = (sflag != 0);

  // WG-local gate column: ncol = jj*4 + gate (interleaved so one 16-wide
  // N-tile carries all 4 gates of 4 h-units -> c-update stays local).
  const int ncol = wv * 16 + nl;
  const int jj   = ncol >> 2;
  const int gate = ncol & 3;
  const int gcol = gate * HID + hg * 16 + jj;  // global row of W_hh/W_ih

  // ---- preload B fragments (weights) into registers, reused all 512 steps
  bf16x8 breg[NKI];
#pragma unroll
  for (int kk = 0; kk < NKI; ++kk) {
    int k0 = kk * 32 + kq * 8;
    if (k0 < HID)
      breg[kk] = load8(W_hh, (size_t)gcol * HID + k0, fp32m);
    else
      breg[kk] = load8(W_ih, (size_t)gcol * FEA + (k0 - HID), fp32m);
  }
  const float bias = loadf(b_ih, gcol, fp32m) + loadf(b_hh, gcol, fp32m);

  // activation-phase ownership: thread -> (batch rows abr, abr+16) x h-unit ajj
  const int ajj = tid & 15;
  const int abr = tid >> 4;              // 0..15
  float c0 = 0.0f, c1 = 0.0f;

  uint32_t* cnt = bar + bg * 64;         // one 256B-isolated counter per group

  for (int t = 0; t < T_STEPS; ++t) {
    // ---- stage A = [h_{t-1}(512) | x_t(64)] into LDS ----
    const uint16_t* hr = hbuf + (size_t)(t & 1) * (256 * 512);
    if (t == 0) {
#pragma unroll
      for (int i = 0; i < 8; ++i) {
        int idx = tid + i * 256, row = idx >> 6, ch = idx & 63;
        *(uint4*)&Als[row * KPAD + ch * 8] = make_uint4(0, 0, 0, 0);
      }
    } else {
#pragma unroll
      for (int i = 0; i < 8; ++i) {
        int idx = tid + i * 256, row = idx >> 6, ch = idx & 63;
        uint4 v = *(const uint4*)&hr[(size_t)(bg * 32 + row) * HID + ch * 8];
        *(uint4*)&Als[row * KPAD + ch * 8] = v;
      }
    }
    {
      int row = tid >> 3, ch = tid & 7;
      size_t off = (size_t)(bg * 32 + row) * (T_STEPS * FEA)
                   + (size_t)t * FEA + ch * 8;
      V8 v;
      if (fp32m) {
        const float* p = (const float*)x + off;
#pragma unroll
        for (int i = 0; i < 8; ++i) v.u[i] = f2bf(p[i]);
      } else {
        v.q = *(const uint4*)((const uint16_t*)x + off);
      }
      *(uint4*)&Als[row * KPAD + HID + ch * 8] = v.q;
    }
    __syncthreads();

    // ---- gates = A @ W^T + bias (fp32 accum) ----
    f32x4 acc0, acc1;
    acc0[0] = bias; acc0[1] = bias; acc0[2] = bias; acc0[3] = bias;
    acc1 = acc0;
#pragma unroll
    for (int kk = 0; kk < NKI; ++kk) {
      int koff = kk * 32 + kq * 8;
      bf16x8 a0 = *(const bf16x8*)&Als[nl * KPAD + koff];
      bf16x8 a1 = *(const bf16x8*)&Als[(nl + 16) * KPAD + koff];
      acc0 = __builtin_amdgcn_mfma_f32_16x16x32_bf16(a0, breg[kk], acc0, 0, 0, 0);
      acc1 = __builtin_amdgcn_mfma_f32_16x16x32_bf16(a1, breg[kk], acc1, 0, 0, 0);
    }
#pragma unroll
    for (int r = 0; r < 4; ++r) {
      Gls[(kq * 4 + r) * GSTR + ncol]      = acc0[r];
      Gls[(16 + kq * 4 + r) * GSTR + ncol] = acc1[r];
    }
    __syncthreads();

    // ---- activations, cell update, h write (bf16, double-buffered) ----
    uint16_t* hw = hbuf + (size_t)((t + 1) & 1) * (256 * 512);
    {
      const float* g0 = &Gls[abr * GSTR + ajj * 4];
      float i0 = sigmoid_f(g0[0]), f0 = sigmoid_f(g0[1]);
      float gg0 = tanh_f(g0[2]),   o0 = sigmoid_f(g0[3]);
      c0 = f0 * c0 + i0 * gg0;
      float h0 = o0 * tanh_f(c0);
      hw[(size_t)(bg * 32 + abr) * HID + hg * 16 + ajj] = f2bf(h0);

      const float* g1 = &Gls[(abr + 16) * GSTR + ajj * 4];
      float i1 = sigmoid_f(g1[0]), f1 = sigmoid_f(g1[1]);
      float gg1 = tanh_f(g1[2]),   o1 = sigmoid_f(g1[3]);
      c1 = f1 * c1 + i1 * gg1;
      float h1 = o1 * tanh_f(c1);
      hw[(size_t)(bg * 32 + abr + 16) * HID + hg * 16 + ajj] = f2bf(h1);
    }

    // ---- group barrier (32 WGs sharing this batch group) ----
    __threadfence();               // agent-scope: publish h stores
    __syncthreads();
    if (tid == 0) {
      __hip_atomic_fetch_add(cnt, 1u, __ATOMIC_RELEASE, __HIP_MEMORY_SCOPE_AGENT);
      uint32_t target = 32u * (uint32_t)(t + 1);
      while (__hip_atomic_load(cnt, __ATOMIC_ACQUIRE, __HIP_MEMORY_SCOPE_AGENT)
             < target) {
        __builtin_amdgcn_s_sleep(2);
      }
    }
    __syncthreads();
  }

  // ---- FC head: out = h_T @ W_fc^T + b_fc  (h_T is in buffer 0) ----
  const uint16_t* hn = hbuf;
  int gwave = hg * 4 + wv;                 // 0..127 within the batch group
  for (int tile = gwave; tile < 192; tile += 128) {
    int mt = tile / 96;                    // 2 M-tiles x 96 N-tiles
    int nt = tile - mt * 96;
    int m0 = bg * 32 + mt * 16;
    int n  = nt * 16 + nl;
    float bs = loadf(b_fc, n, fp32m);
    f32x4 acc; acc[0] = bs; acc[1] = bs; acc[2] = bs; acc[3] = bs;
#pragma unroll
    for (int kk = 0; kk < 16; ++kk) {
      int k0 = kk * 32 + kq * 8;
      V8 av; av.q = *(const uint4*)&hn[(size_t)(m0 + nl) * HID + k0];
      bf16x8 b = load8(W_fc, (size_t)n * HID + k0, fp32m);
      acc = __builtin_amdgcn_mfma_f32_16x16x32_bf16(av.b, b, acc, 0, 0, 0);
    }
#pragma unroll
    for (int r = 0; r < 4; ++r) {
      int row = m0 + kq * 4 + r;
      if (fp32m) ((float*)out)[(size_t)row * 1536 + n] = acc[r];
      else       ((uint16_t*)out)[(size_t)row * 1536 + n] = f2bf(acc[r]);
    }
  }
}

extern "C" void kernel_launch(void* const* d_in, const int* in_sizes, int n_in,
                              void* d_out, int out_size, void* d_ws, size_t ws_size,
                              hipStream_t stream) {
  const void* x    = d_in[0];
  const void* W_ih = d_in[1];
  const void* W_hh = d_in[2];
  const void* b_ih = d_in[3];
  const void* b_hh = d_in[4];
  const void* W_fc = d_in[5];
  const void* b_fc = d_in[6];
  uint16_t* hbuf = (uint16_t*)d_ws;
  uint32_t* bar  = (uint32_t*)((char*)d_ws + BAR_OFF);

  // barrier counters must start at 0 (ws is poisoned 0xAA each call)
  hipMemsetAsync((void*)bar, 0, 8 * 64 * sizeof(uint32_t), stream);

  lstm_persistent<<<dim3(256), dim3(256), 0, stream>>>(
      x, W_ih, W_hh, b_ih, b_hh, W_fc, b_fc, d_out, hbuf, bar);
}

// Round 3
// 4312.574 us; speedup vs baseline: 3.2443x; 3.2443x over previous
//
#include <hip/hip_runtime.h>
#include <stdint.h>

// LSTM_Trend: B=256, T=512, F=64, H=512, P=24.
// Persistent kernel: 128 WGs x 512 threads = 8 batch-groups (32 batches) x
// 16 hidden-groups (32 h-units -> 128 gate columns). Weights register-resident
// as MFMA B-fragments (K = 512 W_hh + 64 W_ih = 576); input projection folded
// into the recurrence GEMM. Cross-WG h exchange via sc1 (L2-bypass) relaxed
// agent atomics; per-step 16-WG barrier = release fetch_add + RELAXED polls +
// one acquire load (no per-poll buffer_inv -> no L2 invalidate storm).

namespace {
constexpr int T_STEPS = 512;
constexpr int FEA  = 64;
constexpr int HID  = 512;
constexpr int KTOT = HID + FEA;   // 576
constexpr int KPAD = KTOT + 8;    // 584: 1168 B rows, b128-friendly
constexpr int NKI  = KTOT / 32;   // 18 K-iterations
constexpr int GSTR = 132;         // gates LDS row stride (floats)
constexpr size_t HBUF_HALF = 256ull * 512;          // bf16 elems per buffer
constexpr size_t BAR_OFF   = 2 * HBUF_HALF * 2;     // byte offset of counters

typedef __bf16   bf16x8 __attribute__((ext_vector_type(8)));
typedef uint16_t u16x8  __attribute__((ext_vector_type(8)));
typedef float    f32x4  __attribute__((ext_vector_type(4)));

union V8 { u16x8 u; bf16x8 b; uint4 q; };

__device__ __forceinline__ float bf2f(uint16_t u) {
  union { uint32_t i; float f; } v; v.i = (uint32_t)u << 16; return v.f;
}
__device__ __forceinline__ uint16_t f2bf(float f) {
  union { float f; uint32_t i; } v; v.f = f;
  uint32_t x = v.i;
  return (uint16_t)((x + 0x7FFFu + ((x >> 16) & 1u)) >> 16);  // RNE
}
__device__ __forceinline__ float sigmoid_f(float x) {
  return 1.0f / (1.0f + __expf(-x));
}
__device__ __forceinline__ float tanh_f(float x) {
  float e = __expf(-2.0f * fabsf(x));
  float t = (1.0f - e) / (1.0f + e);
  return copysignf(t, x);
}
__device__ __forceinline__ bf16x8 load8(const void* base, size_t elem_off,
                                        bool fp32m) {
  V8 r;
  if (fp32m) {
    const float* p = (const float*)base + elem_off;
#pragma unroll
    for (int i = 0; i < 8; ++i) r.u[i] = f2bf(p[i]);
  } else {
    r.q = *(const uint4*)((const uint16_t*)base + elem_off);
  }
  return r.b;
}
__device__ __forceinline__ float loadf(const void* base, int idx, bool fp32m) {
  return fp32m ? ((const float*)base)[idx] : bf2f(((const uint16_t*)base)[idx]);
}
// sc1 (L2-bypass, L3-coherent) relaxed agent atomics for cross-WG h traffic
__device__ __forceinline__ uint32_t ld_a32(const uint32_t* p) {
  return __hip_atomic_load(p, __ATOMIC_RELAXED, __HIP_MEMORY_SCOPE_AGENT);
}
__device__ __forceinline__ void st_a32(uint32_t* p, uint32_t v) {
  __hip_atomic_store(p, v, __ATOMIC_RELAXED, __HIP_MEMORY_SCOPE_AGENT);
}
} // namespace

__global__ __launch_bounds__(512, 1) void lstm_persistent(
    const void* __restrict__ x,      // [256][512][64]
    const void* __restrict__ W_ih,   // [2048][64]
    const void* __restrict__ W_hh,   // [2048][512]
    const void* __restrict__ b_ih,   // [2048]
    const void* __restrict__ b_hh,   // [2048]
    const void* __restrict__ W_fc,   // [1536][512]
    const void* __restrict__ b_fc,   // [1536]
    void* __restrict__ out,          // [256][1536]
    uint16_t* __restrict__ hbuf,     // [2][256][512] bf16 (workspace)
    uint32_t* __restrict__ bar)      // 8 counters, stride 64 uints
{
  __shared__ uint16_t Als[32 * KPAD];    // A tile: [h_{t-1} | x_t], 32 rows
  __shared__ float    Gls[32 * GSTR];    // gate pre-activations, fp32
  __shared__ int      sflag;

  const int tid = threadIdx.x;
  const int wv  = tid >> 6;              // wave 0..7
  const int ln  = tid & 63;
  const int nl  = ln & 15;               // MFMA m/n lane index
  const int kq  = ln >> 4;               // MFMA k-quad
  const int bg  = blockIdx.x & 7;        // batch group (XCD-affine heuristic)
  const int wgi = blockIdx.x >> 3;       // hidden group 0..15

  // ---- dtype sniff (block-uniform): fp32 read as bf16 -> huge exponents
  if (tid == 0) sflag = 0;
  __syncthreads();
  {
    float a = fabsf(bf2f(((const uint16_t*)b_ih)[tid]));
    if (a > 1.0f) atomicOr(&sflag, 1);
  }
  __syncthreads();
  const bool fp32m = (sflag != 0);

  // gate column: ncol = jj*4 + gate (one 16-wide N-tile carries all 4 gates
  // of 4 h-units so the c-update stays thread-local).
  const int ncol = wv * 16 + nl;         // 0..127
  const int jj   = ncol >> 2;            // local h-unit 0..31
  const int gate = ncol & 3;
  const int gcol = gate * HID + wgi * 32 + jj;

  // ---- preload B fragments (weights), reused all 512 steps
  bf16x8 breg[NKI];
#pragma unroll
  for (int kk = 0; kk < NKI; ++kk) {
    int k0 = kk * 32 + kq * 8;
    if (k0 < HID)
      breg[kk] = load8(W_hh, (size_t)gcol * HID + k0, fp32m);
    else
      breg[kk] = load8(W_ih, (size_t)gcol * FEA + (k0 - HID), fp32m);
  }
  const float bias = loadf(b_ih, gcol, fp32m) + loadf(b_hh, gcol, fp32m);

  // activation ownership: row ar (0..31), two adjacent local units au, au+1
  const int ar = tid >> 4;
  const int au = (tid & 15) * 2;
  const int hdw = (bg * 32 + ar) * 256 + wgi * 16 + (tid & 15); // h dword idx
  float c0 = 0.0f, c1 = 0.0f;

  // staging: thread -> row srow, 16 consecutive h dwords at sdw
  const int srow = tid >> 4;
  const int sdw  = (tid & 15) * 16;

  uint32_t* cnt = bar + bg * 64;

  for (int t = 0; t < T_STEPS; ++t) {
    // ---- stage A = [h_{t-1}(512) | x_t(64)] into LDS ----
    uint16_t* Ar = &Als[srow * KPAD];
    if (t == 0) {
#pragma unroll
      for (int i = 0; i < 4; ++i)
        *(uint4*)&Ar[sdw * 2 + i * 8] = make_uint4(0, 0, 0, 0);
    } else {
      const uint32_t* src = (const uint32_t*)(hbuf + (size_t)(t & 1) * HBUF_HALF)
                            + (size_t)(bg * 32 + srow) * 256 + sdw;
      uint32_t v[16];
#pragma unroll
      for (int i = 0; i < 16; ++i) v[i] = ld_a32(src + i);
#pragma unroll
      for (int i = 0; i < 16; ++i) *(uint32_t*)&Ar[sdw * 2 + i * 2] = v[i];
    }
    {
      int xo = (tid & 15) * 4;
      size_t off = (size_t)(bg * 32 + srow) * (T_STEPS * FEA)
                   + (size_t)t * FEA + xo;
      uint2 w;
      if (fp32m) {
        const float* xp = (const float*)x + off;
        float4 xv = *(const float4*)xp;
        w.x = (uint32_t)f2bf(xv.x) | ((uint32_t)f2bf(xv.y) << 16);
        w.y = (uint32_t)f2bf(xv.z) | ((uint32_t)f2bf(xv.w) << 16);
      } else {
        w = *(const uint2*)((const uint16_t*)x + off);
      }
      *(uint2*)&Ar[HID + xo] = w;
    }
    __syncthreads();

    // ---- gates = A @ W^T + bias (fp32 accum) ----
    f32x4 acc0, acc1;
    acc0[0] = bias; acc0[1] = bias; acc0[2] = bias; acc0[3] = bias;
    acc1 = acc0;
#pragma unroll
    for (int kk = 0; kk < NKI; ++kk) {
      int koff = kk * 32 + kq * 8;
      bf16x8 a0 = *(const bf16x8*)&Als[nl * KPAD + koff];
      bf16x8 a1 = *(const bf16x8*)&Als[(nl + 16) * KPAD + koff];
      acc0 = __builtin_amdgcn_mfma_f32_16x16x32_bf16(a0, breg[kk], acc0, 0, 0, 0);
      acc1 = __builtin_amdgcn_mfma_f32_16x16x32_bf16(a1, breg[kk], acc1, 0, 0, 0);
    }
#pragma unroll
    for (int r = 0; r < 4; ++r) {
      Gls[(kq * 4 + r) * GSTR + ncol]      = acc0[r];
      Gls[(16 + kq * 4 + r) * GSTR + ncol] = acc1[r];
    }
    __syncthreads();

    // ---- activations, cell update, packed h store (sc1, L2-bypass) ----
    {
      const f32x4* gp = (const f32x4*)&Gls[ar * GSTR + au * 4];
      f32x4 ga = gp[0], gb = gp[1];
      c0 = sigmoid_f(ga[1]) * c0 + sigmoid_f(ga[0]) * tanh_f(ga[2]);
      float h0 = sigmoid_f(ga[3]) * tanh_f(c0);
      c1 = sigmoid_f(gb[1]) * c1 + sigmoid_f(gb[0]) * tanh_f(gb[2]);
      float h1 = sigmoid_f(gb[3]) * tanh_f(c1);
      uint32_t hp = (uint32_t)f2bf(h0) | ((uint32_t)f2bf(h1) << 16);
      uint32_t* hw = (uint32_t*)(hbuf + (size_t)((t + 1) & 1) * HBUF_HALF);
      st_a32(hw + hdw, hp);
    }

    // ---- 16-WG group barrier: release add, relaxed polls, one acquire ----
    __syncthreads();   // drains vmcnt: all h stores of this WG are complete
    if (tid == 0) {
      __hip_atomic_fetch_add(cnt, 1u, __ATOMIC_RELEASE, __HIP_MEMORY_SCOPE_AGENT);
      uint32_t target = 16u * (uint32_t)(t + 1);
      while (__hip_atomic_load(cnt, __ATOMIC_RELAXED, __HIP_MEMORY_SCOPE_AGENT)
             < target) {
        __builtin_amdgcn_s_sleep(1);
      }
      (void)__hip_atomic_load(cnt, __ATOMIC_ACQUIRE, __HIP_MEMORY_SCOPE_AGENT);
    }
    __syncthreads();
  }

  // ---- FC head: out = h_T @ W_fc^T + b_fc  (h_T is in buffer 0) ----
  const uint32_t* hn = (const uint32_t*)hbuf;
  int gwave = wgi * 8 + wv;                // 0..127 within the batch group
  for (int tile = gwave; tile < 192; tile += 128) {
    int mt = tile / 96;                    // 2 M-tiles x 96 N-tiles
    int nt = tile - mt * 96;
    int m0 = bg * 32 + mt * 16;
    int n  = nt * 16 + nl;
    float bs = loadf(b_fc, n, fp32m);
    f32x4 acc; acc[0] = bs; acc[1] = bs; acc[2] = bs; acc[3] = bs;
#pragma unroll
    for (int kk = 0; kk < 16; ++kk) {
      int k0 = kk * 32 + kq * 8;
      const uint32_t* hp = hn + (size_t)(m0 + nl) * 256 + (k0 >> 1);
      V8 av;
      uint32_t d0 = ld_a32(hp + 0), d1 = ld_a32(hp + 1);
      uint32_t d2 = ld_a32(hp + 2), d3 = ld_a32(hp + 3);
      av.q = make_uint4(d0, d1, d2, d3);
      bf16x8 b = load8(W_fc, (size_t)n * HID + k0, fp32m);
      acc = __builtin_amdgcn_mfma_f32_16x16x32_bf16(av.b, b, acc, 0, 0, 0);
    }
#pragma unroll
    for (int r = 0; r < 4; ++r) {
      int row = m0 + kq * 4 + r;
      if (fp32m) ((float*)out)[(size_t)row * 1536 + n] = acc[r];
      else       ((uint16_t*)out)[(size_t)row * 1536 + n] = f2bf(acc[r]);
    }
  }
}

extern "C" void kernel_launch(void* const* d_in, const int* in_sizes, int n_in,
                              void* d_out, int out_size, void* d_ws, size_t ws_size,
                              hipStream_t stream) {
  const void* x    = d_in[0];
  const void* W_ih = d_in[1];
  const void* W_hh = d_in[2];
  const void* b_ih = d_in[3];
  const void* b_hh = d_in[4];
  const void* W_fc = d_in[5];
  const void* b_fc = d_in[6];
  uint16_t* hbuf = (uint16_t*)d_ws;
  uint32_t* bar  = (uint32_t*)((char*)d_ws + BAR_OFF);

  // barrier counters must start at 0 (ws is poisoned 0xAA each call)
  hipMemsetAsync((void*)bar, 0, 8 * 64 * sizeof(uint32_t), stream);

  lstm_persistent<<<dim3(128), dim3(512), 0, stream>>>(
      x, W_ih, W_hh, b_ih, b_hh, W_fc, b_fc, d_out, hbuf, bar);
}

// Round 4
// 2412.438 us; speedup vs baseline: 5.7997x; 1.7876x over previous
//
#include <hip/hip_runtime.h>
#include <stdint.h>

// LSTM_Trend: B=256, T=512, F=64, H=512, P=24.
// Persistent kernel: 128 WGs x 512 threads = 8 batch-groups (32 batches) x
// 16 hidden-groups (32 h-units -> 128 gate columns). Weights register-resident
// as MFMA B-fragments (K = 512 W_hh + 64 W_ih = 576). Cross-WG h exchange via
// explicit sc0sc1 (L1/L2-bypass, L3-coherent) asm loads/stores. Per-step
// 16-WG barrier = RELEASE fetch_add (wbl2 orders h->counter into L3) +
// RELAXED sc1 polls. NO acquire / buffer_inv anywhere in the hot loop.

namespace {
constexpr int T_STEPS = 512;
constexpr int FEA  = 64;
constexpr int HID  = 512;
constexpr int KTOT = HID + FEA;   // 576
constexpr int KPAD = KTOT + 8;    // 584 bf16 = 1168 B rows (4-dword skew)
constexpr int NKI  = KTOT / 32;   // 18 K-iterations
constexpr int GSTR = 132;         // gates LDS row stride (floats)
constexpr size_t HBUF_HALF = 256ull * 512;          // bf16 elems per buffer
constexpr size_t BAR_OFF   = 2 * HBUF_HALF * 2;     // byte offset of counters

typedef __bf16   bf16x8 __attribute__((ext_vector_type(8)));
typedef uint16_t u16x8  __attribute__((ext_vector_type(8)));
typedef float    f32x4  __attribute__((ext_vector_type(4)));
typedef uint32_t u32x4  __attribute__((ext_vector_type(4)));

union V8 { u16x8 u; bf16x8 b; u32x4 q; };

__device__ __forceinline__ float bf2f(uint16_t u) {
  union { uint32_t i; float f; } v; v.i = (uint32_t)u << 16; return v.f;
}
__device__ __forceinline__ uint16_t f2bf(float f) {
  union { float f; uint32_t i; } v; v.f = f;
  uint32_t x = v.i;
  return (uint16_t)((x + 0x7FFFu + ((x >> 16) & 1u)) >> 16);  // RNE
}
__device__ __forceinline__ float sigmoid_f(float x) {
  return 1.0f / (1.0f + __expf(-x));
}
__device__ __forceinline__ float tanh_f(float x) {
  float e = __expf(-2.0f * fabsf(x));
  float t = (1.0f - e) / (1.0f + e);
  return copysignf(t, x);
}
__device__ __forceinline__ bf16x8 load8(const void* base, size_t elem_off,
                                        bool fp32m) {
  V8 r;
  if (fp32m) {
    const float* p = (const float*)base + elem_off;
#pragma unroll
    for (int i = 0; i < 8; ++i) r.u[i] = f2bf(p[i]);
  } else {
    r.q = *(const u32x4*)((const uint16_t*)base + elem_off);
  }
  return r.b;
}
__device__ __forceinline__ float loadf(const void* base, int idx, bool fp32m) {
  return fp32m ? ((const float*)base)[idx] : bf2f(((const uint16_t*)base)[idx]);
}

// ---- explicit L3-coherent (L1/L2-bypass) memory ops -----------------------
__device__ __forceinline__ uint32_t ld32_sc01(const uint32_t* p) {
  uint32_t v;
  asm volatile("global_load_dword %0, %1, off sc0 sc1"
               : "=v"(v) : "v"(p) : "memory");
  return v;
}
__device__ __forceinline__ u32x4 ld128_sc01(const uint32_t* p) {
  u32x4 v;
  asm volatile("global_load_dwordx4 %0, %1, off sc0 sc1"
               : "=v"(v) : "v"(p) : "memory");
  return v;
}
__device__ __forceinline__ void st32_sc01(uint32_t* p, uint32_t v) {
  asm volatile("global_store_dword %0, %1, off sc0 sc1"
               :: "v"(p), "v"(v) : "memory");
}
__device__ __forceinline__ void waitcnt_vm0() {
  asm volatile("s_waitcnt vmcnt(0)" ::: "memory");
}
} // namespace

__global__ __launch_bounds__(512, 1) void lstm_persistent(
    const void* __restrict__ x,      // [256][512][64]
    const void* __restrict__ W_ih,   // [2048][64]
    const void* __restrict__ W_hh,   // [2048][512]
    const void* __restrict__ b_ih,   // [2048]
    const void* __restrict__ b_hh,   // [2048]
    const void* __restrict__ W_fc,   // [1536][512]
    const void* __restrict__ b_fc,   // [1536]
    void* __restrict__ out,          // [256][1536]
    uint16_t* __restrict__ hbuf,     // [2][256][512] bf16 (workspace)
    uint32_t* __restrict__ bar)      // 8 counters, stride 64 uints
{
  __shared__ uint16_t Als[32 * KPAD];    // A tile: [h_{t-1} | x_t], 32 rows
  __shared__ float    Gls[32 * GSTR];    // gate pre-activations, fp32
  __shared__ int      sflag;

  const int tid = threadIdx.x;
  const int wv  = tid >> 6;              // wave 0..7
  const int ln  = tid & 63;
  const int nl  = ln & 15;               // MFMA m/n lane index
  const int kq  = ln >> 4;               // MFMA k-quad
  const int bg  = blockIdx.x & 7;        // batch group
  const int wgi = blockIdx.x >> 3;       // hidden group 0..15

  // ---- dtype sniff (block-uniform): fp32 read as bf16 -> huge exponents
  if (tid == 0) sflag = 0;
  __syncthreads();
  {
    float a = fabsf(bf2f(((const uint16_t*)b_ih)[tid]));
    if (a > 1.0f) atomicOr(&sflag, 1);
  }
  __syncthreads();
  const bool fp32m = (sflag != 0);

  // gate column: ncol = jj*4 + gate (one 16-wide N-tile carries all 4 gates
  // of 4 h-units so the c-update stays thread-local).
  const int ncol = wv * 16 + nl;         // 0..127
  const int jj   = ncol >> 2;            // local h-unit 0..31
  const int gate = ncol & 3;
  const int gcol = gate * HID + wgi * 32 + jj;

  // ---- preload B fragments (weights), reused all 512 steps
  bf16x8 breg[NKI];
#pragma unroll
  for (int kk = 0; kk < NKI; ++kk) {
    int k0 = kk * 32 + kq * 8;
    if (k0 < HID)
      breg[kk] = load8(W_hh, (size_t)gcol * HID + k0, fp32m);
    else
      breg[kk] = load8(W_ih, (size_t)gcol * FEA + (k0 - HID), fp32m);
  }
  const float bias = loadf(b_ih, gcol, fp32m) + loadf(b_hh, gcol, fp32m);

  // activation ownership: row ar (0..31), two adjacent local units au, au+1
  const int ar  = tid >> 4;
  const int au  = (tid & 15) * 2;
  const int hdw = (bg * 32 + ar) * 256 + wgi * 16 + (tid & 15); // h dword idx
  float c0 = 0.0f, c1 = 0.0f;

  // staging: thread -> row srow, 4 x 16B chunks interleaved at 256B stride
  // (bank-conflict-free: 2-way only)
  const int srow = tid >> 4;
  const int l16  = tid & 15;

  uint32_t* cnt = bar + bg * 64;

  for (int t = 0; t < T_STEPS; ++t) {
    // ---- stage A = [h_{t-1}(512) | x_t(64)] into LDS ----
    uint16_t* Ar = &Als[srow * KPAD];
    if (t == 0) {
#pragma unroll
      for (int i = 0; i < 4; ++i) {
        u32x4 z = {0, 0, 0, 0};
        *(u32x4*)&Ar[(l16 + 16 * i) * 8] = z;
      }
    } else {
      const uint32_t* src =
          (const uint32_t*)(hbuf + (size_t)(t & 1) * HBUF_HALF)
          + (size_t)(bg * 32 + srow) * 256;
      u32x4 v0 = ld128_sc01(src + (l16 + 0)  * 4);
      u32x4 v1 = ld128_sc01(src + (l16 + 16) * 4);
      u32x4 v2 = ld128_sc01(src + (l16 + 32) * 4);
      u32x4 v3 = ld128_sc01(src + (l16 + 48) * 4);
      waitcnt_vm0();
      *(u32x4*)&Ar[(l16 + 0)  * 8] = v0;
      *(u32x4*)&Ar[(l16 + 16) * 8] = v1;
      *(u32x4*)&Ar[(l16 + 32) * 8] = v2;
      *(u32x4*)&Ar[(l16 + 48) * 8] = v3;
    }
    {
      int xo = l16 * 4;
      size_t off = (size_t)(bg * 32 + srow) * (T_STEPS * FEA)
                   + (size_t)t * FEA + xo;
      uint2 w;
      if (fp32m) {
        const float* xp = (const float*)x + off;
        float4 xv = *(const float4*)xp;
        w.x = (uint32_t)f2bf(xv.x) | ((uint32_t)f2bf(xv.y) << 16);
        w.y = (uint32_t)f2bf(xv.z) | ((uint32_t)f2bf(xv.w) << 16);
      } else {
        w = *(const uint2*)((const uint16_t*)x + off);
      }
      *(uint2*)&Ar[HID + xo] = w;
    }
    __syncthreads();

    // ---- gates = A @ W^T + bias (fp32 accum) ----
    f32x4 acc0, acc1;
    acc0[0] = bias; acc0[1] = bias; acc0[2] = bias; acc0[3] = bias;
    acc1 = acc0;
#pragma unroll
    for (int kk = 0; kk < NKI; ++kk) {
      int koff = kk * 32 + kq * 8;
      bf16x8 a0 = *(const bf16x8*)&Als[nl * KPAD + koff];
      bf16x8 a1 = *(const bf16x8*)&Als[(nl + 16) * KPAD + koff];
      acc0 = __builtin_amdgcn_mfma_f32_16x16x32_bf16(a0, breg[kk], acc0, 0, 0, 0);
      acc1 = __builtin_amdgcn_mfma_f32_16x16x32_bf16(a1, breg[kk], acc1, 0, 0, 0);
    }
#pragma unroll
    for (int r = 0; r < 4; ++r) {
      Gls[(kq * 4 + r) * GSTR + ncol]      = acc0[r];
      Gls[(16 + kq * 4 + r) * GSTR + ncol] = acc1[r];
    }
    __syncthreads();

    // ---- activations, cell update, packed h store (sc0sc1 -> L3) ----
    {
      const f32x4* gp = (const f32x4*)&Gls[ar * GSTR + au * 4];
      f32x4 ga = gp[0], gb = gp[1];
      c0 = sigmoid_f(ga[1]) * c0 + sigmoid_f(ga[0]) * tanh_f(ga[2]);
      float h0 = sigmoid_f(ga[3]) * tanh_f(c0);
      c1 = sigmoid_f(gb[1]) * c1 + sigmoid_f(gb[0]) * tanh_f(gb[2]);
      float h1 = sigmoid_f(gb[3]) * tanh_f(c1);
      uint32_t hp = (uint32_t)f2bf(h0) | ((uint32_t)f2bf(h1) << 16);
      uint32_t* hw = (uint32_t*)(hbuf + (size_t)((t + 1) & 1) * HBUF_HALF);
      st32_sc01(hw + hdw, hp);
    }
    waitcnt_vm0();     // asm store is invisible to the compiler's barrier wait
    __syncthreads();   // all waves' h stores drained

    // ---- 16-WG group barrier: release add + relaxed sc1 polls ----
    if (tid == 0) {
      __hip_atomic_fetch_add(cnt, 1u, __ATOMIC_RELEASE,
                             __HIP_MEMORY_SCOPE_AGENT);
      uint32_t target = 16u * (uint32_t)(t + 1);
      for (;;) {
        uint32_t c = ld32_sc01(cnt);
        waitcnt_vm0();
        if (c >= target) break;
        __builtin_amdgcn_s_sleep(1);
      }
    }
    __syncthreads();
  }

  // ---- FC head: out = h_T @ W_fc^T + b_fc  (h_T is in buffer 0) ----
  const uint32_t* hn = (const uint32_t*)hbuf;
  int gwave = wgi * 8 + wv;                // 0..127 within the batch group
  for (int tile = gwave; tile < 192; tile += 128) {
    int mt = tile / 96;                    // 2 M-tiles x 96 N-tiles
    int nt = tile - mt * 96;
    int m0 = bg * 32 + mt * 16;
    int n  = nt * 16 + nl;
    float bs = loadf(b_fc, n, fp32m);
    f32x4 acc; acc[0] = bs; acc[1] = bs; acc[2] = bs; acc[3] = bs;
#pragma unroll
    for (int kk = 0; kk < 16; ++kk) {
      int k0 = kk * 32 + kq * 8;
      V8 av;
      av.q = ld128_sc01(hn + (size_t)(m0 + nl) * 256 + (k0 >> 1));
      bf16x8 b = load8(W_fc, (size_t)n * HID + k0, fp32m);
      waitcnt_vm0();
      acc = __builtin_amdgcn_mfma_f32_16x16x32_bf16(av.b, b, acc, 0, 0, 0);
    }
#pragma unroll
    for (int r = 0; r < 4; ++r) {
      int row = m0 + kq * 4 + r;
      if (fp32m) ((float*)out)[(size_t)row * 1536 + n] = acc[r];
      else       ((uint16_t*)out)[(size_t)row * 1536 + n] = f2bf(acc[r]);
    }
  }
}

extern "C" void kernel_launch(void* const* d_in, const int* in_sizes, int n_in,
                              void* d_out, int out_size, void* d_ws, size_t ws_size,
                              hipStream_t stream) {
  const void* x    = d_in[0];
  const void* W_ih = d_in[1];
  const void* W_hh = d_in[2];
  const void* b_ih = d_in[3];
  const void* b_hh = d_in[4];
  const void* W_fc = d_in[5];
  const void* b_fc = d_in[6];
  uint16_t* hbuf = (uint16_t*)d_ws;
  uint32_t* bar  = (uint32_t*)((char*)d_ws + BAR_OFF);

  // barrier counters must start at 0 (ws is poisoned 0xAA each call)
  hipMemsetAsync((void*)bar, 0, 8 * 64 * sizeof(uint32_t), stream);

  lstm_persistent<<<dim3(128), dim3(512), 0, stream>>>(
      x, W_ih, W_hh, b_ih, b_hh, W_fc, b_fc, d_out, hbuf, bar);
}

// Round 5
// 1846.773 us; speedup vs baseline: 7.5761x; 1.3063x over previous
//
#include <hip/hip_runtime.h>
#include <stdint.h>

// LSTM_Trend: B=256, T=512, F=64, H=512, P=24.
// Persistent kernel: 128 WGs x 512 threads = 8 batch-groups (32 batches) x
// 16 hidden-groups (32 h-units -> 128 gate columns). Weights register-resident
// as MFMA B-fragments (K = 512 W_hh + 64 W_ih = 576). Cross-WG h exchange via
// explicit sc0sc1 (L1/L2-bypass, L3-coherent) asm loads/stores.
// Barrier protocol (zero cache-maintenance): h stores drained by vmcnt(0),
// then fire-and-forget RELAXED global_atomic_add sc1, pollers spin on raw
// sc0sc1 loads. L3 is the serialization point; no wbl2 / buffer_inv anywhere.
// x_{t+1} staging is overlapped with the barrier wait.

namespace {
constexpr int T_STEPS = 512;
constexpr int FEA  = 64;
constexpr int HID  = 512;
constexpr int KTOT = HID + FEA;   // 576
constexpr int KPAD = KTOT + 8;    // 584 bf16 = 1168 B rows (4-dword skew)
constexpr int NKI  = KTOT / 32;   // 18 K-iterations
constexpr int GSTR = 132;         // gates LDS row stride (floats)
constexpr size_t HBUF_HALF = 256ull * 512;          // bf16 elems per buffer
constexpr size_t BAR_OFF   = 2 * HBUF_HALF * 2;     // byte offset of counters

typedef __bf16   bf16x8 __attribute__((ext_vector_type(8)));
typedef uint16_t u16x8  __attribute__((ext_vector_type(8)));
typedef float    f32x4  __attribute__((ext_vector_type(4)));
typedef uint32_t u32x4  __attribute__((ext_vector_type(4)));

union V8 { u16x8 u; bf16x8 b; u32x4 q; };

__device__ __forceinline__ float bf2f(uint16_t u) {
  union { uint32_t i; float f; } v; v.i = (uint32_t)u << 16; return v.f;
}
__device__ __forceinline__ uint16_t f2bf(float f) {
  union { float f; uint32_t i; } v; v.f = f;
  uint32_t x = v.i;
  return (uint16_t)((x + 0x7FFFu + ((x >> 16) & 1u)) >> 16);  // RNE
}
__device__ __forceinline__ float sigmoid_f(float x) {
  return 1.0f / (1.0f + __expf(-x));
}
__device__ __forceinline__ float tanh_f(float x) {
  float e = __expf(-2.0f * fabsf(x));
  float t = (1.0f - e) / (1.0f + e);
  return copysignf(t, x);
}
__device__ __forceinline__ bf16x8 load8(const void* base, size_t elem_off,
                                        bool fp32m) {
  V8 r;
  if (fp32m) {
    const float* p = (const float*)base + elem_off;
#pragma unroll
    for (int i = 0; i < 8; ++i) r.u[i] = f2bf(p[i]);
  } else {
    r.q = *(const u32x4*)((const uint16_t*)base + elem_off);
  }
  return r.b;
}
__device__ __forceinline__ float loadf(const void* base, int idx, bool fp32m) {
  return fp32m ? ((const float*)base)[idx] : bf2f(((const uint16_t*)base)[idx]);
}

// ---- explicit L3-coherent (L1/L2-bypass) memory ops -----------------------
__device__ __forceinline__ uint32_t ld32_sc01(const uint32_t* p) {
  uint32_t v;
  asm volatile("global_load_dword %0, %1, off sc0 sc1"
               : "=v"(v) : "v"(p) : "memory");
  return v;
}
__device__ __forceinline__ u32x4 ld128_sc01(const uint32_t* p) {
  u32x4 v;
  asm volatile("global_load_dwordx4 %0, %1, off sc0 sc1"
               : "=v"(v) : "v"(p) : "memory");
  return v;
}
__device__ __forceinline__ void st32_sc01(uint32_t* p, uint32_t v) {
  asm volatile("global_store_dword %0, %1, off sc0 sc1"
               :: "v"(p), "v"(v) : "memory");
}
// fire-and-forget relaxed atomic add, routed to L3 (sc1), no fences
__device__ __forceinline__ void atomic_add_sc1(uint32_t* p, uint32_t v) {
  asm volatile("global_atomic_add %0, %1, off sc1"
               :: "v"(p), "v"(v) : "memory");
}
__device__ __forceinline__ void waitcnt_vm0() {
  asm volatile("s_waitcnt vmcnt(0)" ::: "memory");
}
} // namespace

__global__ __launch_bounds__(512, 1) void lstm_persistent(
    const void* __restrict__ x,      // [256][512][64]
    const void* __restrict__ W_ih,   // [2048][64]
    const void* __restrict__ W_hh,   // [2048][512]
    const void* __restrict__ b_ih,   // [2048]
    const void* __restrict__ b_hh,   // [2048]
    const void* __restrict__ W_fc,   // [1536][512]
    const void* __restrict__ b_fc,   // [1536]
    void* __restrict__ out,          // [256][1536]
    uint16_t* __restrict__ hbuf,     // [2][256][512] bf16 (workspace)
    uint32_t* __restrict__ bar)      // 8 counters, stride 64 uints
{
  __shared__ uint16_t Als[32 * KPAD];    // A tile: [h_{t-1} | x_t], 32 rows
  __shared__ float    Gls[32 * GSTR];    // gate pre-activations, fp32
  __shared__ int      sflag;

  const int tid = threadIdx.x;
  const int wv  = tid >> 6;              // wave 0..7
  const int ln  = tid & 63;
  const int nl  = ln & 15;               // MFMA m/n lane index
  const int kq  = ln >> 4;               // MFMA k-quad
  const int bg  = blockIdx.x & 7;        // batch group
  const int wgi = blockIdx.x >> 3;       // hidden group 0..15

  // ---- dtype sniff (block-uniform): fp32 read as bf16 -> huge exponents
  if (tid == 0) sflag = 0;
  __syncthreads();
  {
    float a = fabsf(bf2f(((const uint16_t*)b_ih)[tid]));
    if (a > 1.0f) atomicOr(&sflag, 1);
  }
  __syncthreads();
  const bool fp32m = (sflag != 0);

  // gate column: ncol = jj*4 + gate (one 16-wide N-tile carries all 4 gates
  // of 4 h-units so the c-update stays thread-local).
  const int ncol = wv * 16 + nl;         // 0..127
  const int jj   = ncol >> 2;            // local h-unit 0..31
  const int gate = ncol & 3;
  const int gcol = gate * HID + wgi * 32 + jj;

  // ---- preload B fragments (weights), reused all 512 steps
  bf16x8 breg[NKI];
#pragma unroll
  for (int kk = 0; kk < NKI; ++kk) {
    int k0 = kk * 32 + kq * 8;
    if (k0 < HID)
      breg[kk] = load8(W_hh, (size_t)gcol * HID + k0, fp32m);
    else
      breg[kk] = load8(W_ih, (size_t)gcol * FEA + (k0 - HID), fp32m);
  }
  const float bias = loadf(b_ih, gcol, fp32m) + loadf(b_hh, gcol, fp32m);

  // activation ownership: row ar (0..31), two adjacent local units au, au+1
  const int ar  = tid >> 4;
  const int au  = (tid & 15) * 2;
  const int hdw = (bg * 32 + ar) * 256 + wgi * 16 + (tid & 15); // h dword idx
  float c0 = 0.0f, c1 = 0.0f;

  // staging: thread -> row srow; h: 4 x 16B chunks interleaved at 256B
  const int srow = tid >> 4;
  const int l16  = tid & 15;
  uint16_t* Ar = &Als[srow * KPAD];

  uint32_t* cnt = bar + bg * 64;

  // ---- prologue: h_0 = 0 in LDS, stage x_0 ----
  {
    u32x4 z = {0, 0, 0, 0};
#pragma unroll
    for (int i = 0; i < 4; ++i) *(u32x4*)&Ar[(l16 + 16 * i) * 8] = z;
    int xo = l16 * 4;
    size_t off = (size_t)(bg * 32 + srow) * (T_STEPS * FEA) + xo;
    uint2 w;
    if (fp32m) {
      const float4 xv = *(const float4*)((const float*)x + off);
      w.x = (uint32_t)f2bf(xv.x) | ((uint32_t)f2bf(xv.y) << 16);
      w.y = (uint32_t)f2bf(xv.z) | ((uint32_t)f2bf(xv.w) << 16);
    } else {
      w = *(const uint2*)((const uint16_t*)x + off);
    }
    *(uint2*)&Ar[HID + xo] = w;
  }

  for (int t = 0; t < T_STEPS; ++t) {
    __syncthreads();                     // S1: A tile staged

    // ---- gates = A @ W^T + bias (fp32 accum) ----
    f32x4 acc0, acc1;
    acc0[0] = bias; acc0[1] = bias; acc0[2] = bias; acc0[3] = bias;
    acc1 = acc0;
#pragma unroll
    for (int kk = 0; kk < NKI; ++kk) {
      int koff = kk * 32 + kq * 8;
      bf16x8 a0 = *(const bf16x8*)&Als[nl * KPAD + koff];
      bf16x8 a1 = *(const bf16x8*)&Als[(nl + 16) * KPAD + koff];
      acc0 = __builtin_amdgcn_mfma_f32_16x16x32_bf16(a0, breg[kk], acc0, 0, 0, 0);
      acc1 = __builtin_amdgcn_mfma_f32_16x16x32_bf16(a1, breg[kk], acc1, 0, 0, 0);
    }
#pragma unroll
    for (int r = 0; r < 4; ++r) {
      Gls[(kq * 4 + r) * GSTR + ncol]      = acc0[r];
      Gls[(16 + kq * 4 + r) * GSTR + ncol] = acc1[r];
    }
    __syncthreads();                     // S2: gates ready, Als free

    // ---- activations, cell update, packed h store (sc0sc1 -> L3) ----
    {
      const f32x4* gp = (const f32x4*)&Gls[ar * GSTR + au * 4];
      f32x4 ga = gp[0], gb = gp[1];
      c0 = sigmoid_f(ga[1]) * c0 + sigmoid_f(ga[0]) * tanh_f(ga[2]);
      float h0 = sigmoid_f(ga[3]) * tanh_f(c0);
      c1 = sigmoid_f(gb[1]) * c1 + sigmoid_f(gb[0]) * tanh_f(gb[2]);
      float h1 = sigmoid_f(gb[3]) * tanh_f(c1);
      uint32_t hp = (uint32_t)f2bf(h0) | ((uint32_t)f2bf(h1) << 16);
      uint32_t* hw = (uint32_t*)(hbuf + (size_t)((t + 1) & 1) * HBUF_HALF);
      st32_sc01(hw + hdw, hp);
    }
    waitcnt_vm0();                       // h stores of this wave are at L3
    __syncthreads();                     // S3: whole WG's h drained

    // ---- arrive (fire-and-forget), stage x_{t+1} (overlap), poll ----
    if (tid == 0) atomic_add_sc1(cnt, 1u);
    if (t + 1 < T_STEPS) {
      int xo = l16 * 4;
      size_t off = (size_t)(bg * 32 + srow) * (T_STEPS * FEA)
                   + (size_t)(t + 1) * FEA + xo;
      uint2 w;
      if (fp32m) {
        const float4 xv = *(const float4*)((const float*)x + off);
        w.x = (uint32_t)f2bf(xv.x) | ((uint32_t)f2bf(xv.y) << 16);
        w.y = (uint32_t)f2bf(xv.z) | ((uint32_t)f2bf(xv.w) << 16);
      } else {
        w = *(const uint2*)((const uint16_t*)x + off);
      }
      *(uint2*)&Ar[HID + xo] = w;
    }
    if (tid == 0) {
      uint32_t target = 16u * (uint32_t)(t + 1);
      for (;;) {
        uint32_t c = ld32_sc01(cnt);
        waitcnt_vm0();
        if (c >= target) break;
      }
    }
    __syncthreads();                     // S4: barrier passed

    // ---- load h_{t+1} (sc0sc1, straight from L3) into LDS ----
    if (t + 1 < T_STEPS) {
      const uint32_t* src =
          (const uint32_t*)(hbuf + (size_t)((t + 1) & 1) * HBUF_HALF)
          + (size_t)(bg * 32 + srow) * 256;
      u32x4 v0 = ld128_sc01(src + (l16 + 0)  * 4);
      u32x4 v1 = ld128_sc01(src + (l16 + 16) * 4);
      u32x4 v2 = ld128_sc01(src + (l16 + 32) * 4);
      u32x4 v3 = ld128_sc01(src + (l16 + 48) * 4);
      waitcnt_vm0();
      *(u32x4*)&Ar[(l16 + 0)  * 8] = v0;
      *(u32x4*)&Ar[(l16 + 16) * 8] = v1;
      *(u32x4*)&Ar[(l16 + 32) * 8] = v2;
      *(u32x4*)&Ar[(l16 + 48) * 8] = v3;
    }
  }

  // ---- FC head: out = h_T @ W_fc^T + b_fc  (h_T is in buffer 0) ----
  const uint32_t* hn = (const uint32_t*)hbuf;
  int gwave = wgi * 8 + wv;                // 0..127 within the batch group
  for (int tile = gwave; tile < 192; tile += 128) {
    int mt = tile / 96;                    // 2 M-tiles x 96 N-tiles
    int nt = tile - mt * 96;
    int m0 = bg * 32 + mt * 16;
    int n  = nt * 16 + nl;
    float bs = loadf(b_fc, n, fp32m);
    f32x4 acc; acc[0] = bs; acc[1] = bs; acc[2] = bs; acc[3] = bs;
#pragma unroll
    for (int kk = 0; kk < 16; ++kk) {
      int k0 = kk * 32 + kq * 8;
      V8 av;
      av.q = ld128_sc01(hn + (size_t)(m0 + nl) * 256 + (k0 >> 1));
      bf16x8 b = load8(W_fc, (size_t)n * HID + k0, fp32m);
      waitcnt_vm0();
      acc = __builtin_amdgcn_mfma_f32_16x16x32_bf16(av.b, b, acc, 0, 0, 0);
    }
#pragma unroll
    for (int r = 0; r < 4; ++r) {
      int row = m0 + kq * 4 + r;
      if (fp32m) ((float*)out)[(size_t)row * 1536 + n] = acc[r];
      else       ((uint16_t*)out)[(size_t)row * 1536 + n] = f2bf(acc[r]);
    }
  }
}

extern "C" void kernel_launch(void* const* d_in, const int* in_sizes, int n_in,
                              void* d_out, int out_size, void* d_ws, size_t ws_size,
                              hipStream_t stream) {
  const void* x    = d_in[0];
  const void* W_ih = d_in[1];
  const void* W_hh = d_in[2];
  const void* b_ih = d_in[3];
  const void* b_hh = d_in[4];
  const void* W_fc = d_in[5];
  const void* b_fc = d_in[6];
  uint16_t* hbuf = (uint16_t*)d_ws;
  uint32_t* bar  = (uint32_t*)((char*)d_ws + BAR_OFF);

  // barrier counters must start at 0 (ws is poisoned 0xAA each call)
  hipMemsetAsync((void*)bar, 0, 8 * 64 * sizeof(uint32_t), stream);

  lstm_persistent<<<dim3(128), dim3(512), 0, stream>>>(
      x, W_ih, W_hh, b_ih, b_hh, W_fc, b_fc, d_out, hbuf, bar);
}

// Round 6
// 1431.583 us; speedup vs baseline: 9.7733x; 1.2900x over previous
//
#include <hip/hip_runtime.h>
#include <stdint.h>

// LSTM_Trend: B=256, T=512, F=64, H=512, P=24.
// Persistent kernel: 256 WGs x 256 threads (1/CU, whole chip) =
// 16 batch-groups (16 rows) x 16 hidden-groups (32 h-units = 128 gate cols).
// Weights register-resident as MFMA B-fragments (144 VGPRs: 2 subtiles x 18 K);
// each wave reads ONE A-frag per K-step and feeds 2 MFMAs (4x less LDS traffic
// than the 512-thread layout). Cross-WG h via sc0sc1 (L1/L2-bypass, L3-
// coherent) asm ops. Barrier: per-WG flag dwords in one 64B line per group --
// producer stores t+1 after vmcnt(0) h-drain, lanes 0..15 poll their own
// dword (monotone counter, no acquire, no RMW serialization, zero cache
// maintenance in the hot loop).

namespace {
constexpr int T_STEPS = 512;
constexpr int FEA  = 64;
constexpr int HID  = 512;
constexpr int KTOT = HID + FEA;   // 576
constexpr int KPAD = KTOT + 8;    // 584 bf16 = 1168 B rows (16B skew)
constexpr int NKI  = KTOT / 32;   // 18 K-iterations
constexpr int GSTR = 132;         // gates LDS row stride (floats)
constexpr int RPG  = 16;          // batch rows per group
constexpr size_t HBUF_HALF = 256ull * 512;          // bf16 elems per buffer
constexpr size_t BAR_OFF   = 2 * HBUF_HALF * 2;     // byte offset of flags

typedef __bf16   bf16x8 __attribute__((ext_vector_type(8)));
typedef uint16_t u16x8  __attribute__((ext_vector_type(8)));
typedef float    f32x4  __attribute__((ext_vector_type(4)));
typedef uint32_t u32x4  __attribute__((ext_vector_type(4)));

union V8 { u16x8 u; bf16x8 b; u32x4 q; };

__device__ __forceinline__ float bf2f(uint16_t u) {
  union { uint32_t i; float f; } v; v.i = (uint32_t)u << 16; return v.f;
}
__device__ __forceinline__ uint16_t f2bf(float f) {
  union { float f; uint32_t i; } v; v.f = f;
  uint32_t x = v.i;
  return (uint16_t)((x + 0x7FFFu + ((x >> 16) & 1u)) >> 16);  // RNE
}
__device__ __forceinline__ float sigmoid_f(float x) {
  return 1.0f / (1.0f + __expf(-x));
}
__device__ __forceinline__ float tanh_f(float x) {
  float e = __expf(-2.0f * fabsf(x));
  float t = (1.0f - e) / (1.0f + e);
  return copysignf(t, x);
}
__device__ __forceinline__ bf16x8 load8(const void* base, size_t elem_off,
                                        bool fp32m) {
  V8 r;
  if (fp32m) {
    const float* p = (const float*)base + elem_off;
#pragma unroll
    for (int i = 0; i < 8; ++i) r.u[i] = f2bf(p[i]);
  } else {
    r.q = *(const u32x4*)((const uint16_t*)base + elem_off);
  }
  return r.b;
}
__device__ __forceinline__ float loadf(const void* base, int idx, bool fp32m) {
  return fp32m ? ((const float*)base)[idx] : bf2f(((const uint16_t*)base)[idx]);
}

// ---- explicit L3-coherent (L1/L2-bypass) memory ops -----------------------
__device__ __forceinline__ uint32_t ld32_sc01(const uint32_t* p) {
  uint32_t v;
  asm volatile("global_load_dword %0, %1, off sc0 sc1"
               : "=v"(v) : "v"(p) : "memory");
  return v;
}
__device__ __forceinline__ u32x4 ld128_sc01(const uint32_t* p) {
  u32x4 v;
  asm volatile("global_load_dwordx4 %0, %1, off sc0 sc1"
               : "=v"(v) : "v"(p) : "memory");
  return v;
}
__device__ __forceinline__ void st32_sc01(uint32_t* p, uint32_t v) {
  asm volatile("global_store_dword %0, %1, off sc0 sc1"
               :: "v"(p), "v"(v) : "memory");
}
__device__ __forceinline__ void waitcnt_vm0() {
  asm volatile("s_waitcnt vmcnt(0)" ::: "memory");
}
} // namespace

__global__ __launch_bounds__(256, 1) void lstm_persistent(
    const void* __restrict__ x,      // [256][512][64]
    const void* __restrict__ W_ih,   // [2048][64]
    const void* __restrict__ W_hh,   // [2048][512]
    const void* __restrict__ b_ih,   // [2048]
    const void* __restrict__ b_hh,   // [2048]
    const void* __restrict__ W_fc,   // [1536][512]
    const void* __restrict__ b_fc,   // [1536]
    void* __restrict__ out,          // [256][1536]
    uint16_t* __restrict__ hbuf,     // [2][256][512] bf16 (workspace)
    uint32_t* __restrict__ bar)      // 16 groups x 16 flag dwords (64B/line)
{
  __shared__ uint16_t Als[RPG * KPAD];   // A tile: [h_{t-1} | x_t], 16 rows
  __shared__ float    Gls[RPG * GSTR];   // gate pre-activations, fp32
  __shared__ int      sflag;

  const int tid = threadIdx.x;
  const int wv  = tid >> 6;              // wave 0..3
  const int ln  = tid & 63;
  const int nl  = ln & 15;               // MFMA m/n lane index
  const int kq  = ln >> 4;               // MFMA k-quad
  const int bg  = blockIdx.x & 15;       // batch group (XCD-local: 16 % 8 == 0)
  const int wgi = blockIdx.x >> 4;       // hidden group 0..15
  const int r0  = bg * RPG;              // first batch row of this group

  // ---- dtype sniff (block-uniform): fp32 read as bf16 -> huge exponents
  if (tid == 0) sflag = 0;
  __syncthreads();
  {
    float a = fabsf(bf2f(((const uint16_t*)b_ih)[tid]));
    if (a > 1.0f) atomicOr(&sflag, 1);
  }
  __syncthreads();
  const bool fp32m = (sflag != 0);

  // wave owns cols [wv*32, wv*32+32) as two 16-col subtiles sharing one A-frag.
  // col mapping: col = 4*unit + gate  (i,f,g,o of one h-unit in 4 adj cols)
  bf16x8 breg[2][NKI];
  float  bias[2];
#pragma unroll
  for (int s = 0; s < 2; ++s) {
    int col  = wv * 32 + s * 16 + nl;    // 0..127
    int gate = col & 3;
    int unit = col >> 2;                 // 0..31
    int gcol = gate * HID + wgi * 32 + unit;
#pragma unroll
    for (int kk = 0; kk < NKI; ++kk) {
      int k0 = kk * 32 + kq * 8;
      if (k0 < HID)
        breg[s][kk] = load8(W_hh, (size_t)gcol * HID + k0, fp32m);
      else
        breg[s][kk] = load8(W_ih, (size_t)gcol * FEA + (k0 - HID), fp32m);
    }
    bias[s] = loadf(b_ih, gcol, fp32m) + loadf(b_hh, gcol, fp32m);
  }

  // activation ownership: row ar (0..15), units au, au+1
  const int ar  = tid >> 4;
  const int au  = (tid & 15) * 2;
  const int hdw = (r0 + ar) * 256 + wgi * 16 + (tid & 15);  // packed h dword
  float c0 = 0.0f, c1 = 0.0f;

  // staging: thread -> row srow; h: 4 x 16B chunks interleaved at 256B
  const int srow = tid >> 4;
  const int l16  = tid & 15;
  uint16_t* Ar = &Als[srow * KPAD];

  uint32_t* flags = bar + bg * 16;       // this group's 64B flag line

  // ---- prologue: h_0 = 0 in LDS, stage x_0 ----
  {
    u32x4 z = {0, 0, 0, 0};
#pragma unroll
    for (int i = 0; i < 4; ++i) *(u32x4*)&Ar[(l16 + 16 * i) * 8] = z;
    int xo = l16 * 4;
    size_t off = (size_t)(r0 + srow) * (T_STEPS * FEA) + xo;
    uint2 w;
    if (fp32m) {
      const float4 xv = *(const float4*)((const float*)x + off);
      w.x = (uint32_t)f2bf(xv.x) | ((uint32_t)f2bf(xv.y) << 16);
      w.y = (uint32_t)f2bf(xv.z) | ((uint32_t)f2bf(xv.w) << 16);
    } else {
      w = *(const uint2*)((const uint16_t*)x + off);
    }
    *(uint2*)&Ar[HID + xo] = w;
  }

  for (int t = 0; t < T_STEPS; ++t) {
    __syncthreads();                     // S1: A tile staged

    // ---- gates = A @ W^T + bias: 18 K-steps, 1 A-frag -> 2 MFMAs ----
    f32x4 acc0, acc1;
    acc0[0] = bias[0]; acc0[1] = bias[0]; acc0[2] = bias[0]; acc0[3] = bias[0];
    acc1[0] = bias[1]; acc1[1] = bias[1]; acc1[2] = bias[1]; acc1[3] = bias[1];
#pragma unroll
    for (int kk = 0; kk < NKI; ++kk) {
      bf16x8 a = *(const bf16x8*)&Als[nl * KPAD + kk * 32 + kq * 8];
      acc0 = __builtin_amdgcn_mfma_f32_16x16x32_bf16(a, breg[0][kk], acc0, 0, 0, 0);
      acc1 = __builtin_amdgcn_mfma_f32_16x16x32_bf16(a, breg[1][kk], acc1, 0, 0, 0);
    }
#pragma unroll
    for (int r = 0; r < 4; ++r) {
      Gls[(kq * 4 + r) * GSTR + wv * 32 + nl]      = acc0[r];
      Gls[(kq * 4 + r) * GSTR + wv * 32 + 16 + nl] = acc1[r];
    }
    __syncthreads();                     // S2: gates ready, Als free

    // ---- activations, cell update, packed h store (sc0sc1 -> L3) ----
    {
      const f32x4* gp = (const f32x4*)&Gls[ar * GSTR + au * 4];
      f32x4 ga = gp[0], gb = gp[1];
      c0 = sigmoid_f(ga[1]) * c0 + sigmoid_f(ga[0]) * tanh_f(ga[2]);
      float h0 = sigmoid_f(ga[3]) * tanh_f(c0);
      c1 = sigmoid_f(gb[1]) * c1 + sigmoid_f(gb[0]) * tanh_f(gb[2]);
      float h1 = sigmoid_f(gb[3]) * tanh_f(c1);
      uint32_t hp = (uint32_t)f2bf(h0) | ((uint32_t)f2bf(h1) << 16);
      uint32_t* hw = (uint32_t*)(hbuf + (size_t)((t + 1) & 1) * HBUF_HALF);
      st32_sc01(hw + hdw, hp);
    }
    waitcnt_vm0();                       // this wave's h store is at L3
    __syncthreads();                     // S3: whole WG's h drained

    // ---- publish flag, stage x_{t+1} (overlap), poll flags ----
    if (tid == 0) st32_sc01(flags + wgi, (uint32_t)(t + 1));
    if (t + 1 < T_STEPS) {
      int xo = l16 * 4;
      size_t off = (size_t)(r0 + srow) * (T_STEPS * FEA)
                   + (size_t)(t + 1) * FEA + xo;
      uint2 w;
      if (fp32m) {
        const float4 xv = *(const float4*)((const float*)x + off);
        w.x = (uint32_t)f2bf(xv.x) | ((uint32_t)f2bf(xv.y) << 16);
        w.y = (uint32_t)f2bf(xv.z) | ((uint32_t)f2bf(xv.w) << 16);
      } else {
        w = *(const uint2*)((const uint16_t*)x + off);
      }
      *(uint2*)&Ar[HID + xo] = w;
    }
    if (tid < 16) {                      // lane i waits on WG i's flag
      const uint32_t* fp = flags + tid;
      uint32_t target = (uint32_t)(t + 1);
      for (;;) {
        uint32_t c = ld32_sc01(fp);
        waitcnt_vm0();
        if (c >= target) break;
      }
    }
    __syncthreads();                     // S4: barrier passed

    // ---- load h_{t+1} (sc0sc1, straight from L3) into LDS ----
    if (t + 1 < T_STEPS) {
      const uint32_t* src =
          (const uint32_t*)(hbuf + (size_t)((t + 1) & 1) * HBUF_HALF)
          + (size_t)(r0 + srow) * 256;
      u32x4 v0 = ld128_sc01(src + (l16 + 0)  * 4);
      u32x4 v1 = ld128_sc01(src + (l16 + 16) * 4);
      u32x4 v2 = ld128_sc01(src + (l16 + 32) * 4);
      u32x4 v3 = ld128_sc01(src + (l16 + 48) * 4);
      waitcnt_vm0();
      *(u32x4*)&Ar[(l16 + 0)  * 8] = v0;
      *(u32x4*)&Ar[(l16 + 16) * 8] = v1;
      *(u32x4*)&Ar[(l16 + 32) * 8] = v2;
      *(u32x4*)&Ar[(l16 + 48) * 8] = v3;
    }
  }

  // ---- FC head: out = h_T @ W_fc^T + b_fc  (h_T is in buffer 0) ----
  const uint32_t* hn = (const uint32_t*)hbuf;
  int gwave = wgi * 4 + wv;                // 0..63 within the batch group
  for (int tile = gwave; tile < 96; tile += 64) {
    int n = tile * 16 + nl;                // out column
    float bs = loadf(b_fc, n, fp32m);
    f32x4 acc; acc[0] = bs; acc[1] = bs; acc[2] = bs; acc[3] = bs;
#pragma unroll
    for (int kk = 0; kk < 16; ++kk) {
      int k0 = kk * 32 + kq * 8;
      V8 av;
      av.q = ld128_sc01(hn + (size_t)(r0 + nl) * 256 + (k0 >> 1));
      bf16x8 b = load8(W_fc, (size_t)n * HID + k0, fp32m);
      waitcnt_vm0();
      acc = __builtin_amdgcn_mfma_f32_16x16x32_bf16(av.b, b, acc, 0, 0, 0);
    }
#pragma unroll
    for (int r = 0; r < 4; ++r) {
      int row = r0 + kq * 4 + r;
      if (fp32m) ((float*)out)[(size_t)row * 1536 + n] = acc[r];
      else       ((uint16_t*)out)[(size_t)row * 1536 + n] = f2bf(acc[r]);
    }
  }
}

extern "C" void kernel_launch(void* const* d_in, const int* in_sizes, int n_in,
                              void* d_out, int out_size, void* d_ws, size_t ws_size,
                              hipStream_t stream) {
  const void* x    = d_in[0];
  const void* W_ih = d_in[1];
  const void* W_hh = d_in[2];
  const void* b_ih = d_in[3];
  const void* b_hh = d_in[4];
  const void* W_fc = d_in[5];
  const void* b_fc = d_in[6];
  uint16_t* hbuf = (uint16_t*)d_ws;
  uint32_t* bar  = (uint32_t*)((char*)d_ws + BAR_OFF);

  // flags must start at 0 (ws is poisoned 0xAA each call)
  hipMemsetAsync((void*)bar, 0, 16 * 16 * sizeof(uint32_t), stream);

  lstm_persistent<<<dim3(256), dim3(256), 0, stream>>>(
      x, W_ih, W_hh, b_ih, b_hh, W_fc, b_fc, d_out, hbuf, bar);
}